// Round 10
// baseline (120.917 us; speedup 1.0000x reference)
//
#include <hip/hip_runtime.h>

#define COUT_  128
#define CAPR   16              // staged img rows (multiple of 4); +1 zero pad row
#define IMGP   (17 * 64)       // u32 per plane (16 data rows + pad row)
#define IMGBUF (8 * IMGP)      // u32 per group buffer (8 planes)
#define WS_NEED (size_t)(131072 * 2 + 8ull * 64 * 64 * 64 * 4)

#if __has_builtin(__builtin_amdgcn_fdot2_f32_bf16)
#define HAS_DOT2 1
#else
#define HAS_DOT2 0
#endif

typedef __attribute__((ext_vector_type(8))) __bf16 bf16x8;
typedef __attribute__((ext_vector_type(2))) __bf16 bf16x2;
typedef unsigned short u16x8 __attribute__((ext_vector_type(8)));
typedef unsigned int u32x4 __attribute__((ext_vector_type(4)));
typedef __attribute__((ext_vector_type(4))) float f32x4;

__device__ __forceinline__ unsigned int f2bf(float f) {
    union { float f; unsigned int u; } c; c.f = f;
    unsigned int u = c.u;
    u += 0x7fffu + ((u >> 16) & 1u);   // RNE
    return u >> 16;
}
__device__ __forceinline__ float bitsf(unsigned int u) {
    union { unsigned int u; float f; } c; c.u = u; return c.f;
}
__device__ __forceinline__ unsigned int pk2bf(float lo, float hi) {
    return f2bf(lo) | (f2bf(hi) << 16);
}
__device__ __forceinline__ bf16x2 mk_bf2(float lo, float hi) {
    unsigned int u = pk2bf(lo, hi);
    return __builtin_bit_cast(bf16x2, u);
}
__device__ __forceinline__ void gl_lds16(const unsigned int* g, unsigned int* l) {
    __builtin_amdgcn_global_load_lds(
        (const __attribute__((address_space(1))) unsigned int*)g,
        (__attribute__((address_space(3))) unsigned int*)l, 16, 0, 0);
}

// Weights pre-swizzled to MFMA A-fragment order:
//   wbf[((s*8 + mt)*64 + lane)*8 + j] = W[cout = mt*16 + (lane&15)]
//                                        [cin  = 2*s + ((q*8+j)&1)]
//                                        [tap  = (q*8+j)>>1]        (0 if tap > 8)
// where q = lane>>4, s = K-step (cin pair), j = frag element.
__global__ void prep_all(const float* __restrict__ w, unsigned short* __restrict__ wbf,
                         const float* __restrict__ rgb, unsigned int* __restrict__ rgbp,
                         int do_rgb) {
    const int bx = blockIdx.x;
    if (bx < 512) {
        int idx  = bx * 256 + threadIdx.x;    // [0, 131072)
        int j    = idx & 7;
        int lane = (idx >> 3) & 63;
        int mt   = (idx >> 9) & 7;
        int s    = idx >> 12;                 // 0..31
        int ln15 = lane & 15, q = lane >> 4;
        int j2   = q * 8 + j;
        int tap  = j2 >> 1, par = j2 & 1;
        unsigned short v = 0;
        if (j2 < 18)
            v = (unsigned short)f2bf(w[((mt * 16 + ln15) * 64 + s * 2 + par) * 9 + tap]);
        wbf[idx] = v;
    } else if (do_rgb) {
        int idx = (bx - 512) * 256 + threadIdx.x;   // < 2097152
        float a = rgb[idx];
        float nb = ((idx & 63) == 63) ? 0.f : rgb[idx + 1];
        rgbp[idx] = f2bf(a) | (f2bf(nb) << 16);
    }
}

template<bool PREP>
__launch_bounds__(256, 2)
__global__ void deform_mfma10(const float* __restrict__ rgb,
                              const unsigned int* __restrict__ rgbp,
                              const float* __restrict__ off,
                              const unsigned short* __restrict__ wbf,
                              const float* __restrict__ bias,
                              float* __restrict__ out) {
    // img double buffer only — NO col matrix, NO producer/consumer barriers
    __shared__ unsigned int S[2 * IMGBUF];    // 69632 B -> 2 blocks/CU
    __shared__ int sYmin, sYmax;

    const int t    = threadIdx.x;
    const int bid  = blockIdx.x;
    const int b    = bid & 7;                 // XCD pin
    const int ho   = bid >> 3;
    const int lane = t & 63;
    const int wv   = t >> 6;
    const int ln15 = lane & 15;
    const int q    = lane >> 4;
    const int px   = wv * 16 + ln15;          // this lane's pixel (n-index)

    const float* offb = off + b * (2 * 9 * 4096);

    // ---- zero img region once (unwritten rows + pad rows stay 0: NaN-proof) ----
    {
        uint4* S4 = (uint4*)S;
        for (int i = t; i < (2 * IMGBUF) / 4; i += 256) S4[i] = make_uint4(0, 0, 0, 0);
    }
    if (t == 0) { sYmin = 64; sYmax = -1; }
    __syncthreads();

    // ---- meta A: live taps q*4+ti (<=8) at pixel px ----
    float m_fy[4], m_fx[4]; int m_y0[4], m_x0[4], m_live[4];
    int lmin = 64, lmax = -1;
#pragma unroll
    for (int ti = 0; ti < 4; ti++) {
        const int kt = q * 4 + ti;
        m_live[ti] = (kt <= 8);
        if (kt <= 8) {
            const float dy = offb[((2 * kt)     * 64 + ho) * 64 + px];
            const float dx = offb[((2 * kt + 1) * 64 + ho) * 64 + px];
            const float y = (float)(ho - 1 + kt / 3) + dy;
            const float x = (float)(px - 1 + kt % 3) + dx;
            const float y0f = floorf(y), x0f = floorf(x);
            m_fy[ti] = y - y0f; m_fx[ti] = x - x0f;
            m_y0[ti] = (int)y0f; m_x0[ti] = (int)x0f;
            const int r0 = min(max(m_y0[ti], 0), 63), r1 = min(max(m_y0[ti] + 1, 0), 63);
            lmin = min(lmin, r0); lmax = max(lmax, r1);
        } else { m_fy[ti] = 0.f; m_fx[ti] = 0.f; m_y0[ti] = 0; m_x0[ti] = 0; }
    }
    atomicMin(&sYmin, lmin); atomicMax(&sYmax, lmax);
    __syncthreads();
    const int ymin  = sYmin;
    const int nrows = sYmax - ymin + 1;
    const int nr4   = min((nrows + 3) & ~3, CAPR);
    const int ymin2 = max(0, min(ymin, 64 - nr4));

    // ---- staging: group g = cins [8g, 8g+8); wave wv stages planes 2wv, 2wv+1 ----
    auto stage_dma = [&](int g) {
#pragma unroll
        for (int u = 0; u < 2; u++) {
            const int pl = 2 * wv + u;
            const unsigned int* gp = rgbp + ((unsigned)(b * 64 + g * 8 + pl) * 64 + ymin2) * 64 + lane * 4;
            unsigned int* lp = S + (g & 1) * IMGBUF + pl * IMGP;
#pragma unroll
            for (int c = 0; c < 4; c++) {
                const int r4 = c * 4;
                if (r4 < nr4) gl_lds16(gp + r4 * 64, lp + r4 * 64);
            }
        }
    };
    float4 sv[8];
    auto stage_load = [&](int g) {
#pragma unroll
        for (int u = 0; u < 8; u++) {
            const int pl = 2 * wv + (u >> 2), r4 = (u & 3) * 4;
            if (r4 < nr4)
                sv[u] = *(const float4*)(rgb
                    + ((unsigned)(b * 64 + g * 8 + pl) * 64 + ymin2 + r4 + (lane >> 4)) * 64
                    + (lane & 15) * 4);
        }
    };
    auto stage_write = [&](int g) {
#pragma unroll
        for (int u = 0; u < 8; u++) {
            const int pl = 2 * wv + (u >> 2), r4 = (u & 3) * 4;
            const float4 v = sv[u];
            unsigned int b0 = f2bf(v.x), b1 = f2bf(v.y), b2 = f2bf(v.z), b3 = f2bf(v.w);
            unsigned int nb = __shfl(b0, lane + 1);
            if ((lane & 15) == 15) nb = 0;
            if (r4 < nr4) {
                uint4 pk;
                pk.x = b0 | (b1 << 16); pk.y = b1 | (b2 << 16);
                pk.z = b2 | (b3 << 16); pk.w = b3 | (nb << 16);
                *(uint4*)(S + (g & 1) * IMGBUF + pl * IMGP
                          + (r4 + (lane >> 4)) * 64 + (lane & 15) * 4) = pk;
            }
        }
    };

    // ---- meta B: LDS offset + packed corner weights per live tap ----
    int ma[4];
#if HAS_DOT2
    bf16x2 wtp[4], wbp[4];
#else
    float mw[4][4];
#endif
#pragma unroll
    for (int ti = 0; ti < 4; ti++) {
        const int y0 = m_y0[ti], x0 = m_x0[ti];
        const float fy = m_fy[ti], fx = m_fx[ti];
        const int r0 = y0 - ymin2;
        const float wy0 = (y0 >= 0  && y0 < 64) ? (1.f - fy) : 0.f;
        const float wy1 = (y0 >= -1 && y0 < 63) ? fy         : 0.f;
        const bool ylo = (r0 < 0);
        const float wtop = ylo ? wy1 : wy0;
        const float wbot = ylo ? 0.f : wy1;
        const int r0c = ylo ? 0 : min(r0, nr4 - 1);   // bottom row r0c+1 <= 16 (zeroed pad)
        const float wx0 = (x0 >= 0  && x0 < 64) ? (1.f - fx) : 0.f;
        const float wx1 = (x0 >= -1 && x0 < 63) ? fx         : 0.f;
        const bool xlo = (x0 < 0);
        const float wA = xlo ? wx1 : wx0;
        const float wB = xlo ? 0.f : wx1;
        const int xc = min(max(x0, 0), 63);
        ma[ti] = r0c * 64 + xc;
#if HAS_DOT2
        wtp[ti] = mk_bf2(wtop * wA, wtop * wB);
        wbp[ti] = mk_bf2(wbot * wA, wbot * wB);
#else
        mw[ti][0] = wtop * wA; mw[ti][1] = wtop * wB;
        mw[ti][2] = wbot * wA; mw[ti][3] = wbot * wB;
#endif
    }

    f32x4 acc[8] = {};

    auto interp1 = [&](const unsigned int* pl_, int ti) -> float {
        const unsigned int* p = pl_ + ma[ti];
        const unsigned int tp = p[0];     // rows r0c, r0c+1: 256B delta -> ds_read2
        const unsigned int bp = p[64];
#if HAS_DOT2
        float r = __builtin_amdgcn_fdot2_f32_bf16(__builtin_bit_cast(bf16x2, tp), wtp[ti], 0.f, false);
        return  __builtin_amdgcn_fdot2_f32_bf16(__builtin_bit_cast(bf16x2, bp), wbp[ti], r, false);
#else
        return mw[ti][0] * bitsf(tp << 16) + mw[ti][1] * bitsf(tp & 0xffff0000u)
             + mw[ti][2] * bitsf(bp << 16) + mw[ti][3] * bitsf(bp & 0xffff0000u);
#endif
    };

    // 4 K-steps per group, each: build B-frag in registers, 8 coalesced A-loads, 8 MFMA
    auto do_group = [&](int g) {
#pragma unroll
        for (int ps = 0; ps < 4; ps++) {
            const int s = g * 4 + ps;
            const unsigned int* ib = S + (g & 1) * IMGBUF + (2 * ps) * IMGP;
            unsigned int bw[4];
#pragma unroll
            for (int ti = 0; ti < 4; ti++) {
                bw[ti] = 0u;
                if (m_live[ti])    // exec-mask off dead taps (q=2: 3 of 4, q=3: all)
                    bw[ti] = pk2bf(interp1(ib, ti), interp1(ib + IMGP, ti));
            }
            u32x4 bv4 = { bw[0], bw[1], bw[2], bw[3] };
            const bf16x8 bfrag = __builtin_bit_cast(bf16x8, bv4);
            const unsigned short* abase = wbf + ((unsigned)(s * 8) * 64 + lane) * 8;
#pragma unroll
            for (int mt = 0; mt < 8; mt++) {
                const u16x8 au = *(const u16x8*)(abase + mt * 512);
                acc[mt] = __builtin_amdgcn_mfma_f32_16x16x32_bf16(
                    __builtin_bit_cast(bf16x8, au), bfrag, acc[mt], 0, 0, 0);
            }
        }
    };

    if (PREP) stage_dma(0); else { stage_load(0); stage_write(0); }
    __syncthreads();

    for (int g = 0; g < 8; g++) {
        if (g + 1 < 8) { if (PREP) stage_dma(g + 1); else stage_load(g + 1); }
        do_group(g);
        if (!PREP && g + 1 < 8) stage_write(g + 1);
        __syncthreads();   // drains DMA(g+1); all waves done with buf g&1
    }

    // ---- epilogue: C/D map col=ln15 (px), row=q*4+r (cout within 16-tile) ----
#pragma unroll
    for (int mt = 0; mt < 8; mt++) {
#pragma unroll
        for (int r = 0; r < 4; r++) {
            const int cout = mt * 16 + q * 4 + r;
            out[((b * COUT_ + cout) * 64 + ho) * 64 + px] = acc[mt][r] + bias[cout];
        }
    }
}

extern "C" void kernel_launch(void* const* d_in, const int* in_sizes, int n_in,
                              void* d_out, int out_size, void* d_ws, size_t ws_size,
                              hipStream_t stream) {
    const float* rgb  = (const float*)d_in[0];
    const float* off  = (const float*)d_in[1];
    const float* w    = (const float*)d_in[2];
    const float* bias = (const float*)d_in[3];
    float* out = (float*)d_out;
    unsigned short* wbf = (unsigned short*)d_ws;                    // 256 KB
    unsigned int* rgbp  = (unsigned int*)((char*)d_ws + 131072 * 2); // 8.39 MB

    const int do_rgb = (ws_size >= WS_NEED) ? 1 : 0;
    prep_all<<<do_rgb ? 8704 : 512, 256, 0, stream>>>(w, wbf, rgb, rgbp, do_rgb);
    if (do_rgb)
        deform_mfma10<true><<<512, 256, 0, stream>>>(rgb, rgbp, off, wbf, bias, out);
    else
        deform_mfma10<false><<<512, 256, 0, stream>>>(rgb, nullptr, off, wbf, bias, out);
}

// Round 11
// 117.371 us; speedup vs baseline: 1.0302x; 1.0302x over previous
//
#include <hip/hip_runtime.h>
#include <hip/hip_bf16.h>

#define CAPR   16
#define IMGP   (17 * 64)            // u32 per staged plane (16 rows + zero pad row)
#define NS     18                   // K-steps: s<16 -> 4 cins x taps0-7; s>=16 -> tap 8
#define WBF_N  (NS * 8 * 64 * 8)    // 73728 u16
#define RGBP_OFF 147456
#define COL_OFF  (147456 + 8388608)
#define WS_NEED  ((size_t)COL_OFF + 37748736ull)

#if __has_builtin(__builtin_amdgcn_fdot2_f32_bf16)
#define HAS_DOT2 1
#else
#define HAS_DOT2 0
#endif

typedef __attribute__((ext_vector_type(8))) __bf16 bf16x8;
typedef __attribute__((ext_vector_type(2))) __bf16 bf16x2;
typedef unsigned short u16x8 __attribute__((ext_vector_type(8)));
typedef __attribute__((ext_vector_type(4))) float f32x4;

__device__ __forceinline__ unsigned short f2bfu(float f) {
    __hip_bfloat16 h = __float2bfloat16(f);           // RNE
    unsigned short u; __builtin_memcpy(&u, &h, 2); return u;
}
__device__ __forceinline__ unsigned int pk2bf(float lo, float hi) {
    __hip_bfloat162 h = __float22bfloat162_rn(make_float2(lo, hi));
    unsigned int u; __builtin_memcpy(&u, &h, 4); return u;
}
__device__ __forceinline__ bf16x2 mk_bf2(float lo, float hi) {
    unsigned int u = pk2bf(lo, hi);
    return __builtin_bit_cast(bf16x2, u);
}
__device__ __forceinline__ float bitsf(unsigned int u) {
    union { unsigned int u; float f; } c; c.u = u; return c.f;
}
__device__ __forceinline__ void gl_lds16(const unsigned int* g, unsigned int* l) {
    __builtin_amdgcn_global_load_lds(
        (const __attribute__((address_space(1))) unsigned int*)g,
        (__attribute__((address_space(3))) unsigned int*)l, 16, 0, 0);
}

// K mapping (single source of truth; lane = q*16+ln15, frag elem j, j2 = q*8+j):
//   s < 16 : tap = j2>>2, cin = s*4 + (j2&3)
//   s >= 16: tap = 8,     cin = (s-16)*32 + j2
// A storage: wbf[((s*8+mt)*64+lane)*8+j] = W[mt*16+ln15][cin][tap]
// B storage: colp u32 slot (((b*18+s)*256+nt)*64+lane)*4 + (j>>1)
__global__ void prep_all(const float* __restrict__ w, unsigned short* __restrict__ wbf,
                         const float* __restrict__ rgb, unsigned int* __restrict__ rgbp,
                         int do_rgb) {
    const int bx = blockIdx.x;
    if (bx < 288) {
        const int idx = bx * 256 + threadIdx.x;        // < 73728
        const int j = idx & 7, lane = (idx >> 3) & 63, mt = (idx >> 9) & 7, s = idx >> 12;
        const int q = lane >> 4, ln15 = lane & 15;
        const int j2 = q * 8 + j;
        int tap, cin;
        if (s < 16) { tap = j2 >> 2; cin = s * 4 + (j2 & 3); }
        else        { tap = 8;       cin = (s - 16) * 32 + j2; }
        wbf[idx] = f2bfu(w[((mt * 16 + ln15) * 64 + cin) * 9 + tap]);
    } else if (do_rgb) {
        const int idx = (bx - 288) * 256 + threadIdx.x;  // < 2097152
        const float a = rgb[idx];
        const float nb = ((idx & 63) == 63) ? 0.f : rgb[idx + 1];
        rgbp[idx] = pk2bf(a, nb);
    }
}

__launch_bounds__(256, 4)
__global__ void g_gather(const unsigned int* __restrict__ rgbp,
                         const float* __restrict__ off,
                         unsigned int* __restrict__ colp) {
    __shared__ unsigned int S[2 * 4 * IMGP];   // 34816 B -> 4 blocks/CU
    __shared__ int sYmin, sYmax;

    const int t  = threadIdx.x;
    const int bid = blockIdx.x;
    const int b  = bid & 7;            // XCD pin (matches gemm)
    const int ho = bid >> 3;
    const int px = t & 63;
    const int qr = t >> 6;
    const int lane = t & 63;
    const int nt = ho * 4 + (px >> 4);
    const int ln = px & 15;

    const float* offb = off + b * (2 * 9 * 4096);

    {   // zero both bufs once: unwritten rows + pad row stay 0 (NaN-proof)
        uint4* S4 = (uint4*)S;
        for (int i = t; i < (2 * 4 * IMGP) / 4; i += 256) S4[i] = make_uint4(0, 0, 0, 0);
    }
    if (t == 0) { sYmin = 64; sYmax = -1; }

    // ---- meta A: this thread's taps {qr*2, qr*2+1, 8} at pixel px ----
    const int taps[3] = { qr * 2, qr * 2 + 1, 8 };
    float m_fy[3], m_fx[3]; int m_y0[3], m_x0[3];
    int lmin = 64, lmax = -1;
#pragma unroll
    for (int ti = 0; ti < 3; ti++) {
        const int kt = taps[ti];
        const float dy = offb[((2 * kt)     * 64 + ho) * 64 + px];
        const float dx = offb[((2 * kt + 1) * 64 + ho) * 64 + px];
        const float y = (float)(ho - 1 + kt / 3) + dy;
        const float x = (float)(px - 1 + kt % 3) + dx;
        const float y0f = floorf(y), x0f = floorf(x);
        m_fy[ti] = y - y0f; m_fx[ti] = x - x0f;
        m_y0[ti] = (int)y0f; m_x0[ti] = (int)x0f;
        const int r0 = min(max(m_y0[ti], 0), 63), r1 = min(max(m_y0[ti] + 1, 0), 63);
        lmin = min(lmin, r0); lmax = max(lmax, r1);
    }
    atomicMin(&sYmin, lmin); atomicMax(&sYmax, lmax);
    __syncthreads();
    const int ymin  = sYmin;
    const int nrows = sYmax - ymin + 1;
    const int nr4   = min((nrows + 3) & ~3, CAPR);
    const int ymin2 = max(0, min(ymin, 64 - nr4));

    // ---- meta B: one LDS offset per tap (r1 = r0+1 forced) + packed dot2 weights ----
    int ma[3];
#if HAS_DOT2
    bf16x2 wtp[3], wbp[3];
#else
    float mw[3][4];
#endif
#pragma unroll
    for (int ti = 0; ti < 3; ti++) {
        const int y0 = m_y0[ti], x0 = m_x0[ti];
        const float fy = m_fy[ti], fx = m_fx[ti];
        const int r0 = y0 - ymin2;
        const float wy0 = (y0 >= 0  && y0 < 64) ? (1.f - fy) : 0.f;
        const float wy1 = (y0 >= -1 && y0 < 63) ? fy         : 0.f;
        const bool ylo = (r0 < 0);
        const float wtop = ylo ? wy1 : wy0;
        const float wbot = ylo ? 0.f : wy1;
        const int r0c = ylo ? 0 : min(r0, nr4 - 1);   // bottom read row <= 16 (zeroed)
        const float wx0 = (x0 >= 0  && x0 < 64) ? (1.f - fx) : 0.f;
        const float wx1 = (x0 >= -1 && x0 < 63) ? fx         : 0.f;
        const bool xlo = (x0 < 0);
        const float wA = xlo ? wx1 : wx0;
        const float wB = xlo ? 0.f : wx1;
        const int xc = min(max(x0, 0), 63);
        ma[ti] = r0c * 64 + xc;
#if HAS_DOT2
        wtp[ti] = mk_bf2(wtop * wA, wtop * wB);
        wbp[ti] = mk_bf2(wbot * wA, wbot * wB);
#else
        mw[ti][0] = wtop * wA; mw[ti][1] = wtop * wB;
        mw[ti][2] = wbot * wA; mw[ti][3] = wbot * wB;
#endif
    }

    auto interp1 = [&](const unsigned int* pl_, int ti) -> float {
        const unsigned int* p = pl_ + ma[ti];
        const unsigned int tp = p[0];    // rows r0c, r0c+1: const 256B delta -> ds_read2
        const unsigned int bp = p[64];
#if HAS_DOT2
        float r = __builtin_amdgcn_fdot2_f32_bf16(__builtin_bit_cast(bf16x2, tp), wtp[ti], 0.f, false);
        return  __builtin_amdgcn_fdot2_f32_bf16(__builtin_bit_cast(bf16x2, bp), wbp[ti], r, false);
#else
        return mw[ti][0] * bitsf(tp << 16) + mw[ti][1] * bitsf(tp & 0xffff0000u)
             + mw[ti][2] * bitsf(bp << 16) + mw[ti][3] * bitsf(bp & 0xffff0000u);
#endif
    };

    // DMA chunk cc (planes cc*4 .. cc*4+3) into buf cc&1 — issued by ONE wave
    auto dma = [&](int cc) {
        unsigned int* lb = S + (cc & 1) * (4 * IMGP);
        const unsigned int* gb = rgbp + ((unsigned)(b * 64 + cc * 4) * 64 + ymin2) * 64 + lane * 4;
#pragma unroll
        for (int p = 0; p < 4; p++)
#pragma unroll
            for (int c4 = 0; c4 < 4; c4++) {
                const int r4 = c4 * 4;
                if (r4 < nr4) gl_lds16(gb + p * 4096 + r4 * 64, lb + p * IMGP + r4 * 64);
            }
    };

    if (qr == 1) dma(0);
    __syncthreads();

    for (int c = 0; c < 16; c++) {
        if (c + 1 < 16 && qr == ((c + 2) & 3)) dma(c + 1);
        const unsigned int* ib = S + (c & 1) * (4 * IMGP);
        // step c, quad qr: j2 = qr*8 + (0..7): taps {qr*2, qr*2+1} x planes 0..3
        uint4 v;
        v.x = pk2bf(interp1(ib,            0), interp1(ib + IMGP,     0));
        v.y = pk2bf(interp1(ib + 2 * IMGP, 0), interp1(ib + 3 * IMGP, 0));
        v.z = pk2bf(interp1(ib,            1), interp1(ib + IMGP,     1));
        v.w = pk2bf(interp1(ib + 2 * IMGP, 1), interp1(ib + 3 * IMGP, 1));
        *(uint4*)(colp + (((unsigned)(b * NS + c) * 256 + nt) * 64 + qr * 16 + ln) * 4) = v;
        // tap 8 for planes c*4..c*4+3 -> step 16+(c>>3), j2 = (4c)&31 (rotating owner)
        if (qr == (c & 3)) {
            uint2 v8;
            v8.x = pk2bf(interp1(ib,            2), interp1(ib + IMGP,     2));
            v8.y = pk2bf(interp1(ib + 2 * IMGP, 2), interp1(ib + 3 * IMGP, 2));
            const int j2 = (4 * c) & 31, q8 = j2 >> 3, jlo = j2 & 7;
            const int s8 = 16 + (c >> 3);
            *(uint2*)(colp + (((unsigned)(b * NS + s8) * 256 + nt) * 64 + q8 * 16 + ln) * 4
                      + (jlo >> 1)) = v8;
        }
        __syncthreads();
    }
}

__launch_bounds__(256, 2)
__global__ void g_gemm(const unsigned int* __restrict__ colp,
                       const unsigned short* __restrict__ wbf,
                       const float* __restrict__ bias,
                       float* __restrict__ out) {
    const int t = threadIdx.x, bid = blockIdx.x;
    const int b = bid & 7, ntg = bid >> 3;     // XCD pin matches gather
    const int lane = t & 63, wv = t >> 6;
    const int nt = ntg * 4 + wv;
    const int ln15 = lane & 15, q = lane >> 4;

    f32x4 acc[8] = {};
    const unsigned int* bptr = colp + (((unsigned)(b * NS) * 256 + nt) * 64 + lane) * 4;
    const unsigned short* aptr = wbf + (unsigned)lane * 8;

    u16x8 Bc = *(const u16x8*)bptr;
    u16x8 Ac[8];
#pragma unroll
    for (int mt = 0; mt < 8; mt++) Ac[mt] = *(const u16x8*)(aptr + mt * 512);

    for (int s = 0; s < NS; s++) {
        u16x8 Bn = Bc; u16x8 An[8];
#pragma unroll
        for (int mt = 0; mt < 8; mt++) An[mt] = Ac[mt];
        if (s + 1 < NS) {
            Bn = *(const u16x8*)(bptr + (unsigned)(s + 1) * (256 * 64 * 4));
#pragma unroll
            for (int mt = 0; mt < 8; mt++)
                An[mt] = *(const u16x8*)(aptr + ((unsigned)(s + 1) * 8 + mt) * 512);
        }
#pragma unroll
        for (int mt = 0; mt < 8; mt++)
            acc[mt] = __builtin_amdgcn_mfma_f32_16x16x32_bf16(
                __builtin_bit_cast(bf16x8, Ac[mt]), __builtin_bit_cast(bf16x8, Bc),
                acc[mt], 0, 0, 0);
        Bc = Bn;
#pragma unroll
        for (int mt = 0; mt < 8; mt++) Ac[mt] = An[mt];
    }

    const int n = nt * 16 + ln15;
#pragma unroll
    for (int mt = 0; mt < 8; mt++)
#pragma unroll
        for (int r = 0; r < 4; r++) {
            const int cout = mt * 16 + q * 4 + r;
            out[(unsigned)(b * 128 + cout) * 4096 + n] = acc[mt][r] + bias[cout];
        }
}

// insurance only: correct but slow path if ws is unexpectedly small
__global__ void naive_deform(const float* __restrict__ rgb, const float* __restrict__ off,
                             const float* __restrict__ w, const float* __restrict__ bias,
                             float* __restrict__ out) {
    const int idx = blockIdx.x * 256 + threadIdx.x;    // 8*128*4096
    const int n = idx & 4095, cout = (idx >> 12) & 127, b = idx >> 19;
    const int ho = n >> 6, wo = n & 63;
    const float* offb = off + b * (2 * 9 * 4096);
    const float* rgbb = rgb + b * (64 * 4096);
    float acc = bias[cout];
    for (int k = 0; k < 9; k++) {
        const float dy = offb[((2 * k) * 64 + ho) * 64 + wo];
        const float dx = offb[((2 * k + 1) * 64 + ho) * 64 + wo];
        const float y = (float)(ho - 1 + k / 3) + dy;
        const float x = (float)(wo - 1 + k % 3) + dx;
        const float y0f = floorf(y), x0f = floorf(x);
        const float fy = y - y0f, fx = x - x0f;
        const int y0 = (int)y0f, x0 = (int)x0f;
        const bool vy0 = y0 >= 0 && y0 < 64, vy1 = y0 >= -1 && y0 < 63;
        const bool vx0 = x0 >= 0 && x0 < 64, vx1 = x0 >= -1 && x0 < 63;
        const int cy0 = min(max(y0, 0), 63), cy1 = min(max(y0 + 1, 0), 63);
        const int cx0 = min(max(x0, 0), 63), cx1 = min(max(x0 + 1, 0), 63);
        const float w00 = (vy0 && vx0) ? (1 - fy) * (1 - fx) : 0.f;
        const float w01 = (vy0 && vx1) ? (1 - fy) * fx : 0.f;
        const float w10 = (vy1 && vx0) ? fy * (1 - fx) : 0.f;
        const float w11 = (vy1 && vx1) ? fy * fx : 0.f;
        const int i00 = cy0 * 64 + cx0, i01 = cy0 * 64 + cx1;
        const int i10 = cy1 * 64 + cx0, i11 = cy1 * 64 + cx1;
        for (int cin = 0; cin < 64; cin++) {
            const float* img = rgbb + cin * 4096;
            const float v = w00 * img[i00] + w01 * img[i01] + w10 * img[i10] + w11 * img[i11];
            acc += w[(cout * 64 + cin) * 9 + k] * v;
        }
    }
    out[idx] = acc;
}

extern "C" void kernel_launch(void* const* d_in, const int* in_sizes, int n_in,
                              void* d_out, int out_size, void* d_ws, size_t ws_size,
                              hipStream_t stream) {
    const float* rgb  = (const float*)d_in[0];
    const float* off  = (const float*)d_in[1];
    const float* w    = (const float*)d_in[2];
    const float* bias = (const float*)d_in[3];
    float* out = (float*)d_out;
    unsigned short* wbf = (unsigned short*)d_ws;                       // 144 KB
    unsigned int* rgbp  = (unsigned int*)((char*)d_ws + RGBP_OFF);     // 8.39 MB
    unsigned int* colp  = (unsigned int*)((char*)d_ws + COL_OFF);      // 37.75 MB

    if (ws_size >= WS_NEED) {
        prep_all<<<288 + 8192, 256, 0, stream>>>(w, wbf, rgb, rgbp, 1);
        g_gather<<<512, 256, 0, stream>>>(rgbp, off, colp);
        g_gemm<<<512, 256, 0, stream>>>(colp, wbf, bias, out);
    } else {
        naive_deform<<<(8 * 128 * 4096) / 256, 256, 0, stream>>>(rgb, off, w, bias, out);
    }
}